// Round 4
// baseline (121.172 us; speedup 1.0000x reference)
//
#include <hip/hip_runtime.h>
#include <math.h>

#define IMG 416
#define N_ANG 320
#define N_DET 416
#define N_SAMP 416
#define NCHUNK 8
#define CHLEN (N_SAMP / NCHUNK)      // 52 samples per chunk
#define NGRP 7                       // det groups of 64 (last half-masked)

// Packed quad table: rows pr=0..417 map to r0=pr-1 in [-1,416];
// cols pc=0..431 (STRIDE), valid pc=0..417 map to c0=pc-1; rest zero pad.
// Entry = {bf16 v(r0,c0)|v(r0,c0+1)<<16 , bf16 v(r0+1,c0)|v(r0+1,c0+1)<<16}
#define PSTRIDE 432
#define PROWS   418
#define PBYTES  ((size_t)PROWS * PSTRIDE * 8)

static __device__ __forceinline__ unsigned int f2bf(float f) {
    unsigned int x = __float_as_uint(f);
    return (x + 0x7fffu + ((x >> 16) & 1u)) >> 16;   // RNE to bf16
}

// ---------------------------------------------------------------------------
// Kernel A: build the packed quad table from (input - target); zero d_out.
// ---------------------------------------------------------------------------
__global__ __launch_bounds__(256) void pack_kernel(const float* __restrict__ a,
                                                   const float* __restrict__ b,
                                                   uint2* __restrict__ P,
                                                   float* __restrict__ out) {
    int i = blockIdx.x * 256 + threadIdx.x;
    if (i == 0) out[0] = 0.0f;
    if (i >= PROWS * PSTRIDE) return;
    int pr = i / PSTRIDE;
    int pc = i - pr * PSTRIDE;
    int r = pr - 1, c = pc - 1;
    float v00 = 0.f, v01 = 0.f, v10 = 0.f, v11 = 0.f;
    bool c0in = (unsigned)c < (unsigned)IMG;
    bool c1in = (unsigned)(c + 1) < (unsigned)IMG;
    if ((unsigned)r < (unsigned)IMG) {
        int base = r * IMG;
        if (c0in) v00 = a[base + c] - b[base + c];
        if (c1in) v01 = a[base + c + 1] - b[base + c + 1];
    }
    if ((unsigned)(r + 1) < (unsigned)IMG) {
        int base = (r + 1) * IMG;
        if (c0in) v10 = a[base + c] - b[base + c];
        if (c1in) v11 = a[base + c + 1] - b[base + c + 1];
    }
    uint2 u;
    u.x = f2bf(v00) | (f2bf(v01) << 16);
    u.y = f2bf(v10) | (f2bf(v11) << 16);
    P[i] = u;
}

__global__ void zero_out_kernel(float* __restrict__ out) {
    if (threadIdx.x == 0) out[0] = 0.0f;
}

// ---------------------------------------------------------------------------
// Kernel B: block = one angle x 64-det group, 8 waves = 8 sample-chunks.
// Wave lanes = 64 consecutive dets at ONE t -> compact arc footprint that
// advances 1.4 px/iter => high L1 line reuse across iterations. Wave-uniform
// slab clip per chunk. Per-det chunk partials -> LDS -> full ray sum ->
// square -> shuffle reduce -> 1 atomic/block.
// ---------------------------------------------------------------------------
__global__ __launch_bounds__(512) void proj_packed(const uint2* __restrict__ P,
                                                   float* __restrict__ out,
                                                   float theta_step, float gmax,
                                                   float gstep, float t0,
                                                   float dtstep, float coef) {
    const int tid  = threadIdx.x;
    const int lane = tid & 63;
    const int wv   = tid >> 6;                 // chunk id 0..7
    const int gid  = blockIdx.x;               // 0 .. 320*NGRP-1
    const int a    = gid / NGRP;
    const int grp  = gid - a * NGRP;
    const int d    = grp * 64 + lane;          // 0..447 (>=416 masked)
    const bool valid = (d < N_DET);

    const float theta = (float)a * theta_step;
    const float gamma = fmaf((float)d, gstep, -gmax);
    float s1, c1, s2, c2;
    sincosf(theta, &s1, &c1);
    sincosf(theta + gamma, &s2, &c2);
    const float sx = fmaf(1075.0f, c1, 207.5f);
    const float sy = fmaf(1075.0f, s1, 207.5f);

    // --- per-ray slab clip (t range where taps can be nonzero) -------------
    const float c2g = (fabsf(c2) < 1e-12f) ? 1e-12f : c2;
    const float s2g = (fabsf(s2) < 1e-12f) ? 1e-12f : s2;
    const float ix = 1.0f / c2g, iy = 1.0f / s2g;
    const float tax = (sx - 416.5f) * ix, tbx = (sx + 1.5f) * ix;
    const float tay = (sy - 416.5f) * iy, tby = (sy + 1.5f) * iy;
    const float t_lo = fmaxf(fminf(tax, tbx), fminf(tay, tby));
    const float t_hi = fminf(fmaxf(tax, tbx), fmaxf(tay, tby));

    const float tc0 = fmaf((float)(wv * CHLEN), dtstep, t0);
    const float inv_dt = 1.0f / dtstep;
    int jlo = (int)floorf((t_lo - tc0) * inv_dt);
    int jhi = (int)ceilf((t_hi - tc0) * inv_dt);
    jlo = max(0, min(jlo, CHLEN));
    jhi = min(CHLEN - 1, jhi);
    if (!valid) { jlo = CHLEN; jhi = -1; }     // don't widen the union

    // wave-uniform union over the 64 dets
    int ulo = jlo, uhi = jhi;
    #pragma unroll
    for (int m = 1; m < 64; m <<= 1) {
        ulo = min(ulo, __shfl_xor(ulo, m, 64));
        uhi = max(uhi, __shfl_xor(uhi, m, 64));
    }
    ulo = __builtin_amdgcn_readfirstlane(ulo);
    uhi = __builtin_amdgcn_readfirstlane(uhi);

    float acc = 0.0f;
    if (ulo <= uhi) {
        const uint2* __restrict__ Pb = P + (PSTRIDE + 1);  // fold +1 pad offset
        const float tb = fmaf((float)ulo, dtstep, tc0);
        float col = fmaf(-tb, c2, sx);
        float row = fmaf(-tb, s2, sy);
        const float dcol = -dtstep * c2;
        const float drow = -dtstep * s2;

        #pragma unroll 4
        for (int j = ulo; j <= uhi; ++j) {
            // branch-free clamp into the zero-pad ring: indices in [-1,416]
            const float colc = fminf(fmaxf(col, -1.0f), 416.5f);
            const float rowc = fminf(fmaxf(row, -1.0f), 416.5f);
            const int ci = (int)floorf(colc);
            const int ri = (int)floorf(rowc);
            const float wc = colc - (float)ci;
            const float wr = rowc - (float)ri;

            const uint2 u = Pb[ri * PSTRIDE + ci];
            const float v00 = __uint_as_float(u.x << 16);
            const float v01 = __uint_as_float(u.x & 0xffff0000u);
            const float v10 = __uint_as_float(u.y << 16);
            const float v11 = __uint_as_float(u.y & 0xffff0000u);

            const float top = fmaf(wc, v01 - v00, v00);
            const float bot = fmaf(wc, v11 - v10, v10);
            acc = fmaf(wr, bot - top, acc + top);

            col += dcol;
            row += drow;
        }
    }
    if (!valid) acc = 0.0f;

    // combine the 8 chunk-partials of each det, square, reduce, one atomic
    __shared__ float part[NCHUNK][64];
    part[wv][lane] = acc;
    __syncthreads();
    if (tid < 64) {
        float s = part[0][tid];
        #pragma unroll
        for (int w = 1; w < NCHUNK; ++w) s += part[w][tid];
        float sq = s * s;
        #pragma unroll
        for (int m = 1; m < 64; m <<= 1) sq += __shfl_xor(sq, m, 64);
        if (tid == 0) atomicAdd(out, sq * coef);
    }
}

// ---------------------------------------------------------------------------
// Fallback (ws too small): fused one-thread-per-ray fp32 gather version.
// ---------------------------------------------------------------------------
__global__ __launch_bounds__(256) void proj_fused(const float* __restrict__ imgA,
                                                  const float* __restrict__ imgB,
                                                  float* __restrict__ out,
                                                  float theta_step, float gmax,
                                                  float gstep, float t0,
                                                  float dtstep, float coef) {
    const int idx = blockIdx.x * 256 + threadIdx.x;
    const int a  = idx / N_DET;
    const int dd = idx - a * N_DET;
    const float theta = (float)a * theta_step;
    const float gamma = fmaf((float)dd, gstep, -gmax);
    float s1, c1, s2, c2;
    sincosf(theta, &s1, &c1);
    sincosf(theta + gamma, &s2, &c2);
    const float sx = 1075.0f * c1 + 207.5f;
    const float sy = 1075.0f * s1 + 207.5f;
    float acc = 0.0f;
    #pragma unroll 4
    for (int s = 0; s < N_SAMP; ++s) {
        const float t   = fmaf((float)s, dtstep, t0);
        const float col = fmaf(-t, c2, sx);
        const float row = fmaf(-t, s2, sy);
        const float c0 = floorf(col);
        const float r0 = floorf(row);
        const float wc = col - c0;
        const float wr = row - r0;
        const int ci = (int)c0;
        const int ri = (int)r0;
        auto G = [&](int r, int c) -> float {
            if ((unsigned)r < (unsigned)IMG && (unsigned)c < (unsigned)IMG)
                return imgA[r * IMG + c] - imgB[r * IMG + c];
            return 0.0f;
        };
        const float v00 = G(ri, ci);
        const float v01 = G(ri, ci + 1);
        const float v10 = G(ri + 1, ci);
        const float v11 = G(ri + 1, ci + 1);
        const float top = fmaf(wc, v01 - v00, v00);
        const float bot = fmaf(wc, v11 - v10, v10);
        acc += fmaf(wr, bot - top, top);
    }
    float sq = acc * acc;
    #pragma unroll
    for (int o = 32; o > 0; o >>= 1) sq += __shfl_down(sq, o, 64);
    __shared__ float wsum[4];
    const int lane = threadIdx.x & 63;
    if (lane == 0) wsum[threadIdx.x >> 6] = sq;
    __syncthreads();
    if (threadIdx.x == 0)
        atomicAdd(out, (wsum[0] + wsum[1] + wsum[2] + wsum[3]) * coef);
}

extern "C" void kernel_launch(void* const* d_in, const int* in_sizes, int n_in,
                              void* d_out, int out_size, void* d_ws, size_t ws_size,
                              hipStream_t stream) {
    const float* in = (const float*)d_in[0];
    const float* tg = (const float*)d_in[1];
    float* out = (float*)d_out;

    const double half_diag = (IMG / 2.0) * sqrt(2.0);
    const double ray_len   = IMG * sqrt(2.0);
    const float  gmax      = (float)asin(half_diag / 1075.0);
    const float  gstep     = (float)(2.0 * (double)gmax / (N_DET - 1));
    const float  t0        = (float)(1075.0 - ray_len / 2.0);
    const float  dtstep    = (float)(ray_len / (N_SAMP - 1));
    const float  theta_step = (float)(2.0 * M_PI / N_ANG);
    const double dt        = ray_len / (N_SAMP - 1);
    const double SCALE     = 512.0 / 416.0 * 0.03;
    const float  coef      = (float)(dt * dt * SCALE / ((double)N_ANG * N_DET));

    if (ws_size >= PBYTES) {
        uint2* P = (uint2*)d_ws;
        const int n_ent = PROWS * PSTRIDE;
        pack_kernel<<<(n_ent + 255) / 256, 256, 0, stream>>>(in, tg, P, out);
        proj_packed<<<N_ANG * NGRP, 512, 0, stream>>>(
            P, out, theta_step, gmax, gstep, t0, dtstep, coef);
    } else {
        zero_out_kernel<<<1, 64, 0, stream>>>(out);
        proj_fused<<<(N_ANG * N_DET) / 256, 256, 0, stream>>>(
            in, tg, out, theta_step, gmax, gstep, t0, dtstep, coef);
    }
}

// Round 5
// 113.839 us; speedup vs baseline: 1.0644x; 1.0644x over previous
//
#include <hip/hip_runtime.h>
#include <math.h>

#define IMG 416
#define N_ANG 320
#define N_DET 416
#define N_SAMP 416
#define NK (N_SAMP / 8)          // 52 sample-blocks per phase lane

// ---------------------------------------------------------------------------
// fp8 quad table, 4x4-px tiled. Padded pixel coords pr=r+1, pc=c+1 in [0,418).
// Quad(pr,pc) = fp8 e4m3 of padded diff at {(pr,pc),(pr,pc+1),(pr+1,pc),(pr+1,pc+1)}
// packed into one uint (bytes 0,1,2,3). Tile (tr,tc) = 4x4 quads = 64 B = one
// cache line. idx = ((pr>>2)*TW + (pc>>2))*16 + (pr&3)*4 + (pc&3).
// ---------------------------------------------------------------------------
#define TW 105                       // tiles per row/col (ceil(418/4))
#define TABLE_WORDS (TW * TW * 16)   // 176400 words = 705.6 KB
#define TBYTES ((size_t)TABLE_WORDS * 4)

typedef float vfloat2 __attribute__((ext_vector_type(2)));

// ---------------------------------------------------------------------------
// Kernel A: build the tiled fp8 quad table from (input - target); zero d_out.
// ---------------------------------------------------------------------------
__global__ __launch_bounds__(256) void pack_kernel(const float* __restrict__ a,
                                                   const float* __restrict__ b,
                                                   unsigned int* __restrict__ T,
                                                   float* __restrict__ out) {
    int i = blockIdx.x * 256 + threadIdx.x;
    if (i == 0) out[0] = 0.0f;
    if (i >= TABLE_WORDS) return;
    int tile = i >> 4, sub = i & 15;
    int tr = tile / TW, tc = tile - tr * TW;
    int pr = tr * 4 + (sub >> 2);
    int pc = tc * 4 + (sub & 3);
    int r = pr - 1, c = pc - 1;          // pr,pc may reach 419: pad rows, zero
    float v00 = 0.f, v01 = 0.f, v10 = 0.f, v11 = 0.f;
    bool c0in = (unsigned)c < (unsigned)IMG;
    bool c1in = (unsigned)(c + 1) < (unsigned)IMG;
    if ((unsigned)r < (unsigned)IMG) {
        int base = r * IMG;
        if (c0in) v00 = a[base + c] - b[base + c];
        if (c1in) v01 = a[base + c + 1] - b[base + c + 1];
    }
    if ((unsigned)(r + 1) < (unsigned)IMG) {
        int base = (r + 1) * IMG;
        if (c0in) v10 = a[base + c] - b[base + c];
        if (c1in) v11 = a[base + c + 1] - b[base + c + 1];
    }
    unsigned int u = __builtin_amdgcn_cvt_pk_fp8_f32(v00, v01, 0u, false);
    u = __builtin_amdgcn_cvt_pk_fp8_f32(v10, v11, u, true);
    T[i] = u;
}

__global__ void zero_out_kernel(float* __restrict__ out) {
    if (threadIdx.x == 0) out[0] = 0.0f;
}

// ---------------------------------------------------------------------------
// Kernel B (R3 structure): wave = 8 dets x 8 sample-phases, per-ray slab clip
// -> wave-uniform k-loop. One dword gather + 2 HW fp8 unpacks per bilinear
// sample. Butterfly reduce -> square -> LDS -> 1 atomic/block.
// ---------------------------------------------------------------------------
__global__ __launch_bounds__(256) void proj_packed(const unsigned int* __restrict__ T,
                                                   float* __restrict__ out,
                                                   float theta_step, float gmax,
                                                   float gstep, float t0,
                                                   float dtstep, float coef) {
    const int lane = threadIdx.x & 63;
    const int wave = (blockIdx.x * 256 + threadIdx.x) >> 6;
    const int det_base = wave << 3;              // 8 dets/wave; no straddle
    const int a  = det_base / N_DET;
    const int d  = det_base - a * N_DET + (lane >> 3);
    const int s0 = lane & 7;

    const float theta = (float)a * theta_step;
    const float gamma = fmaf((float)d, gstep, -gmax);
    float s1, c1, s2, c2;
    sincosf(theta, &s1, &c1);
    sincosf(theta + gamma, &s2, &c2);
    const float sx = fmaf(1075.0f, c1, 207.5f);
    const float sy = fmaf(1075.0f, s1, 207.5f);

    const float dt8 = 8.0f * dtstep;
    const float tstart = fmaf((float)s0, dtstep, t0);

    // --- slab clip: t-range where taps can be nonzero (as in R3) -----------
    const float c2g = (fabsf(c2) < 1e-12f) ? 1e-12f : c2;
    const float s2g = (fabsf(s2) < 1e-12f) ? 1e-12f : s2;
    const float ix = 1.0f / c2g, iy = 1.0f / s2g;
    const float tax = (sx - 416.5f) * ix, tbx = (sx + 1.5f) * ix;
    const float tay = (sy - 416.5f) * iy, tby = (sy + 1.5f) * iy;
    const float t_lo = fmaxf(fminf(tax, tbx), fminf(tay, tby));
    const float t_hi = fminf(fmaxf(tax, tbx), fmaxf(tay, tby));

    const float inv_dt8 = 1.0f / dt8;
    int klo = (int)floorf((t_lo - tstart) * inv_dt8);
    int khi = (int)ceilf((t_hi - tstart) * inv_dt8);
    klo = max(0, min(klo, NK));
    khi = min(NK - 1, khi);

    #pragma unroll
    for (int m = 1; m < 64; m <<= 1) {
        klo = min(klo, __shfl_xor(klo, m, 64));
        khi = max(khi, __shfl_xor(khi, m, 64));
    }
    klo = __builtin_amdgcn_readfirstlane(klo);
    khi = __builtin_amdgcn_readfirstlane(khi);

    // padded coords: track col+1, row+1 so trunc==floor and clamp is [0,417.5]
    const float tb = fmaf((float)klo, dt8, tstart);
    float colp = fmaf(-tb, c2, sx + 1.0f);
    float rowp = fmaf(-tb, s2, sy + 1.0f);
    const float dcol = -dt8 * c2;
    const float drow = -dt8 * s2;

    float acc = 0.0f;
    #pragma unroll 4
    for (int k = klo; k <= khi; ++k) {
        const float colc = fminf(fmaxf(colp, 0.0f), 417.5f);
        const float rowc = fminf(fmaxf(rowp, 0.0f), 417.5f);
        const int pc = (int)colc;                 // trunc == floor (>=0)
        const int pr = (int)rowc;
        const float wc = colc - (float)pc;
        const float wr = rowc - (float)pr;

        const int idx = (((pr >> 2) * TW + (pc >> 2)) << 4) + ((pr & 3) << 2) + (pc & 3);
        const unsigned int u = T[idx];
        const vfloat2 lo = __builtin_amdgcn_cvt_pk_f32_fp8(u, false);  // v00,v01
        const vfloat2 hi = __builtin_amdgcn_cvt_pk_f32_fp8(u, true);   // v10,v11

        const float top = fmaf(wc, lo[1] - lo[0], lo[0]);
        const float bot = fmaf(wc, hi[1] - hi[0], hi[0]);
        acc = fmaf(wr, bot - top, acc + top);

        colp += dcol;
        rowp += drow;
    }

    // sum over the 8 sample-phases (lane bits 0-2)
    #pragma unroll
    for (int m = 1; m < 8; m <<= 1) acc += __shfl_xor(acc, m, 64);
    float sq = acc * acc;           // identical across each det's 8 lanes
    // sum over the 8 det groups (lane bits 3-5): each group counted once
    #pragma unroll
    for (int m = 8; m < 64; m <<= 1) sq += __shfl_xor(sq, m, 64);

    __shared__ float wsum[4];
    if (lane == 0) wsum[threadIdx.x >> 6] = sq;
    __syncthreads();
    if (threadIdx.x == 0)
        atomicAdd(out, (wsum[0] + wsum[1] + wsum[2] + wsum[3]) * coef);
}

// ---------------------------------------------------------------------------
// Fallback (ws too small): fused one-thread-per-ray fp32 gather version.
// ---------------------------------------------------------------------------
__global__ __launch_bounds__(256) void proj_fused(const float* __restrict__ imgA,
                                                  const float* __restrict__ imgB,
                                                  float* __restrict__ out,
                                                  float theta_step, float gmax,
                                                  float gstep, float t0,
                                                  float dtstep, float coef) {
    const int idx = blockIdx.x * 256 + threadIdx.x;
    const int a  = idx / N_DET;
    const int dd = idx - a * N_DET;
    const float theta = (float)a * theta_step;
    const float gamma = fmaf((float)dd, gstep, -gmax);
    float s1, c1, s2, c2;
    sincosf(theta, &s1, &c1);
    sincosf(theta + gamma, &s2, &c2);
    const float sx = 1075.0f * c1 + 207.5f;
    const float sy = 1075.0f * s1 + 207.5f;
    float acc = 0.0f;
    #pragma unroll 4
    for (int s = 0; s < N_SAMP; ++s) {
        const float t   = fmaf((float)s, dtstep, t0);
        const float col = fmaf(-t, c2, sx);
        const float row = fmaf(-t, s2, sy);
        const float c0 = floorf(col);
        const float r0 = floorf(row);
        const float wc = col - c0;
        const float wr = row - r0;
        const int ci = (int)c0;
        const int ri = (int)r0;
        auto G = [&](int r, int c) -> float {
            if ((unsigned)r < (unsigned)IMG && (unsigned)c < (unsigned)IMG)
                return imgA[r * IMG + c] - imgB[r * IMG + c];
            return 0.0f;
        };
        const float v00 = G(ri, ci);
        const float v01 = G(ri, ci + 1);
        const float v10 = G(ri + 1, ci);
        const float v11 = G(ri + 1, ci + 1);
        const float top = fmaf(wc, v01 - v00, v00);
        const float bot = fmaf(wc, v11 - v10, v10);
        acc += fmaf(wr, bot - top, top);
    }
    float sq = acc * acc;
    #pragma unroll
    for (int o = 32; o > 0; o >>= 1) sq += __shfl_down(sq, o, 64);
    __shared__ float wsum[4];
    const int lane = threadIdx.x & 63;
    if (lane == 0) wsum[threadIdx.x >> 6] = sq;
    __syncthreads();
    if (threadIdx.x == 0)
        atomicAdd(out, (wsum[0] + wsum[1] + wsum[2] + wsum[3]) * coef);
}

extern "C" void kernel_launch(void* const* d_in, const int* in_sizes, int n_in,
                              void* d_out, int out_size, void* d_ws, size_t ws_size,
                              hipStream_t stream) {
    const float* in = (const float*)d_in[0];
    const float* tg = (const float*)d_in[1];
    float* out = (float*)d_out;

    const double half_diag = (IMG / 2.0) * sqrt(2.0);
    const double ray_len   = IMG * sqrt(2.0);
    const float  gmax      = (float)asin(half_diag / 1075.0);
    const float  gstep     = (float)(2.0 * (double)gmax / (N_DET - 1));
    const float  t0        = (float)(1075.0 - ray_len / 2.0);
    const float  dtstep    = (float)(ray_len / (N_SAMP - 1));
    const float  theta_step = (float)(2.0 * M_PI / N_ANG);
    const double dt        = ray_len / (N_SAMP - 1);
    const double SCALE     = 512.0 / 416.0 * 0.03;
    const float  coef      = (float)(dt * dt * SCALE / ((double)N_ANG * N_DET));

    const int n_rays = N_ANG * N_DET;            // 133120
    if (ws_size >= TBYTES) {
        unsigned int* T = (unsigned int*)d_ws;
        pack_kernel<<<(TABLE_WORDS + 255) / 256, 256, 0, stream>>>(in, tg, T, out);
        // 8 dets/wave -> 16640 waves -> 4160 blocks of 4 waves
        proj_packed<<<(n_rays / 8) / 4, 256, 0, stream>>>(
            T, out, theta_step, gmax, gstep, t0, dtstep, coef);
    } else {
        zero_out_kernel<<<1, 64, 0, stream>>>(out);
        proj_fused<<<n_rays / 256, 256, 0, stream>>>(
            in, tg, out, theta_step, gmax, gstep, t0, dtstep, coef);
    }
}